// Round 16
// baseline (218.274 us; speedup 1.0000x reference)
//
#include <hip/hip_runtime.h>

#define HW 2304
#define W48 48
#define NT 15              // timestep partials for the atomic spread
#define RST 17             // transposed Rs: [48 cols][17 rows-pad] floats
#define RS_SIZE (W48 * RST)
#define RXW 128            // rec4x row width (float4), col c holds rec[c%48]
#define NITEMS 5760        // 15t x 48sy x 4 quarters x 2 halves

// ---------------------------------------------------------------------------
// prep: build rec4 (flat, for gather) + rec4x (row-duplicated width-128, for
// dist's literal-offset ring refills) + cur0 + frame-0 output copy; init
// best_part and the two work-stealing counters.
// ---------------------------------------------------------------------------
__global__ __launch_bounds__(256) void prep_kernel(
    const float* __restrict__ x, const float* __restrict__ rec,
    const float* __restrict__ walls,
    float4* __restrict__ rec4, float4* __restrict__ rec4x,
    float4* __restrict__ cur0, float* __restrict__ dout,
    unsigned long long* __restrict__ best_part,
    unsigned int* __restrict__ ctr)
{
    int id = blockIdx.x * 256 + threadIdx.x;
    if (id < 16 * HW) {
        int t = id / HW, p = id % HW;
        int y = p / W48, xx = p % W48;
        float4 v = make_float4(rec[(t * 3 + 0) * HW + p],
                               rec[(t * 3 + 1) * HW + p],
                               rec[(t * 3 + 2) * HW + p],
                               walls[p]);
        rec4[id] = v;
        float4* rowd = rec4x + (size_t)(t * W48 + y) * RXW;
        rowd[xx] = v;
        rowd[xx + 48] = v;
        if (xx < 32) rowd[xx + 96] = v;
    }
    if (id < HW) {
        cur0[id] = make_float4(x[0 * HW + id], x[1 * HW + id], x[2 * HW + id],
                               walls[id]);
    }
    if (id < 3 * HW) {
        dout[id] = x[id];  // frame 0, channels 0..2
    }
    if (id < NT * HW) {
        best_part[id] = ~0ULL;
    }
    if (id < 2) {
        ctr[id] = 0u;
    }
}

// DPP within 16-lane rows. ROW_ROR:N (0x120+N): dest lane i <- src lane
// (i-N) mod 16. Direction pinned by r8's verified row_shl:N = i<-i+N.
template <int CTL>
__device__ __forceinline__ float dppf(float v)
{
    return __int_as_float(__builtin_amdgcn_update_dpp(
        0, __float_as_int(v), CTL, 0xF, 0xF, false));
}
#define ROR1  0x121   // lane i <- lane (i-1) mod 16  (left neighbor's value)
#define ROR15 0x12F   // lane i <- lane (i+1) mod 16  (right neighbor's value)

// ---------------------------------------------------------------------------
// dist v16: r15 inner structure (transposed Rs x4 + 1 barrier per sx-pair,
// DPP halo, literal-offset 6-slot ring, packed-fp32 DIFF) with:
//  - WORK-STEALING persistent blocks: grid = 2048 (exact thread-cap), items
//    (t, sy, quarter, half) pulled via atomicAdd -- kills the 2.8-generation
//    ramp/drain that capped r15 at 60% occupancy. Output via atomicMin is
//    order-independent -> deterministic.
//  - packed argmin via fmin(double): packed (dist_bits<<32|idx) is always a
//    positive finite double (dist < +inf => exp < 0x7FF), so IEEE double
//    ordering == u64 ordering; v_min_f64 = 1 inst vs cmp_lt_u64+2 cndmask.
// Distances/indices bit-identical to rounds 2..15.
// ---------------------------------------------------------------------------
__global__ __launch_bounds__(256) void dist_kernel(
    const float4* __restrict__ rec4x, const float4* __restrict__ cur4,
    unsigned long long* __restrict__ best_part,
    unsigned int* __restrict__ ctr)
{
    __shared__ float Rs[4 * RS_SIZE];      // 13056 B
    __shared__ unsigned int sItem;

    const int tid = threadIdx.x;

    // item-invariant thread geometry
    const int rid = tid >> 4;
    const int cA  = tid & 15;
    const int x0  = 3 * cA;
    const bool cact = tid < 192;
    const int xc  = tid % W48;
    const int y0C = 3 * (tid / W48);
    const double DMAXD = __longlong_as_double(0x7FEFFFFFFFFFFFFFLL);

#define DIFFP(F, CAa, CAb, WAa, WAb) do {                                   \
        float2 dA_ = (CAa) - (WAa);                                         \
        float2 dB_ = (CAb) - (WAb);                                         \
        float2 s_  = dA_ * dA_ + dB_ * dB_;                                 \
        F = s_.x + s_.y;                                                    \
    } while (0)

#define COLMIN(BUF, RX) do {                                                \
        const float* rp = &Rs[(BUF) * RS_SIZE + xc * RST + y0C];            \
        float rv0 = rp[0], rv1 = rp[1], rv2 = rp[2], rv3 = rp[3];           \
        float rv4 = rp[4], rv5 = rp[5], rv6 = rp[6];                        \
        float U_ = rv2 + rv3 + rv4;                                         \
        float D0 = rv0 + rv1 + U_;                                          \
        float D1 = rv1 + U_ + rv5;                                          \
        float D2 = U_ + rv5 + rv6;                                          \
        bst0 = fmin(bst0, __longlong_as_double(                             \
            ((unsigned long long)__float_as_uint(D0) << 32) |               \
            (mb0 + (unsigned)(RX))));                                       \
        bst1 = fmin(bst1, __longlong_as_double(                             \
            ((unsigned long long)__float_as_uint(D1) << 32) |               \
            (mb1 + (unsigned)(RX))));                                       \
        bst2 = fmin(bst2, __longlong_as_double(                             \
            ((unsigned long long)__float_as_uint(D2) << 32) |               \
            (mb2 + (unsigned)(RX))));                                       \
    } while (0)

#define STEP2(PB, J, A0a, A0b, A1a, A1b, A2a, A2b, A3a, A3b) do {           \
        float F0a, F1a, F2a, F0b, F1b, F2b;                                 \
        DIFFP(F0a, cw0a, cw0b, A0a, A0b);                                   \
        DIFFP(F1a, cw1a, cw1b, A1a, A1b);                                   \
        DIFFP(F2a, cw2a, cw2b, A2a, A2b);                                   \
        DIFFP(F0b, cw0a, cw0b, A1a, A1b);                                   \
        DIFFP(F1b, cw1a, cw1b, A2a, A2b);                                   \
        DIFFP(F2b, cw2a, cw2b, A3a, A3b);                                   \
        float Fm2a = dppf<ROR1>(F1a);                                       \
        float Fm1a = dppf<ROR1>(F2a);                                       \
        float F3a  = dppf<ROR15>(F0a);                                      \
        float F4a  = dppf<ROR15>(F1a);                                      \
        float Fm2b = dppf<ROR1>(F1b);                                       \
        float Fm1b = dppf<ROR1>(F2b);                                       \
        float F3b  = dppf<ROR15>(F0b);                                      \
        float F4b  = dppf<ROR15>(F1b);                                      \
        float Ta  = F0a + F1a + F2a;                                        \
        float R0a = Fm2a + Fm1a + Ta;                                       \
        float R1a = Fm1a + Ta + F3a;                                        \
        float R2a = Ta + F3a + F4a;                                         \
        float Tb  = F0b + F1b + F2b;                                        \
        float R0b = Fm2b + Fm1b + Tb;                                       \
        float R1b = Fm1b + Tb + F3b;                                        \
        float R2b = Tb + F3b + F4b;                                         \
        {                                                                   \
            float* wa = &Rs[(PB) * RS_SIZE + x0 * RST + rid];               \
            wa[0 * RST] = R0a; wa[1 * RST] = R1a; wa[2 * RST] = R2a;        \
            float* wb = &Rs[((PB) + 1) * RS_SIZE + x0 * RST + rid];         \
            wb[0 * RST] = R0b; wb[1 * RST] = R1b; wb[2 * RST] = R2b;        \
        }                                                                   \
        {                                                                   \
            float4 v_;                                                      \
            v_ = rb[J];                                                     \
            A0a = make_float2(v_.x, v_.y); A0b = make_float2(v_.z, v_.w);   \
            v_ = rb[(J) + 1];                                               \
            A1a = make_float2(v_.x, v_.y); A1b = make_float2(v_.z, v_.w);   \
        }                                                                   \
        __syncthreads();                                                    \
        if (cact) {                                                         \
            int rxB = rx + 1; if (rxB >= W48) rxB -= W48;                   \
            COLMIN(PB, rx);                                                 \
            COLMIN((PB) + 1, rxB);                                          \
            rx = rxB + 1; if (rx >= W48) rx -= W48;                         \
        } else {                                                            \
            rx += 2; if (rx >= W48) rx -= W48;                              \
        }                                                                   \
    } while (0)

    for (;;) {
        if (tid == 0) sItem = atomicAdd(ctr, 1u);
        __syncthreads();
        const unsigned int item = sItem;
        if (item >= NITEMS) break;

        const int t   = item / 384;
        const int rem = item % 384;
        const int sy  = rem >> 3;
        const int q   = rem & 7;
        const int yq  = q >> 1;
        const int sx0 = (q & 1) * 24;

        int qy = yq * 12 + rid - 2;
        if (qy < 0) qy += W48;
        if (qy >= W48) qy -= W48;
        int ry = qy + sy; if (ry >= W48) ry -= W48;

        const float4* curRow = cur4 + qy * W48;
        const float4 c0 = curRow[x0 + 0];
        const float4 c1 = curRow[x0 + 1];
        const float4 c2 = curRow[x0 + 2];
        const float2 cw0a = make_float2(c0.x, c0.y);
        const float2 cw0b = make_float2(c0.z, c0.w);
        const float2 cw1a = make_float2(c1.x, c1.y);
        const float2 cw1b = make_float2(c1.z, c1.w);
        const float2 cw2a = make_float2(c2.x, c2.y);
        const float2 cw2b = make_float2(c2.z, c2.w);

        const int cb = x0 + sx0;
        const float4* rb = rec4x + (size_t)(t * W48 + ry) * RXW + cb;

        float2 q0a, q0b, q1a, q1b, q2a, q2b, q3a, q3b, q4a, q4b, q5a, q5b;
        {
            float4 v;
            v = rb[0]; q0a = make_float2(v.x, v.y); q0b = make_float2(v.z, v.w);
            v = rb[1]; q1a = make_float2(v.x, v.y); q1b = make_float2(v.z, v.w);
            v = rb[2]; q2a = make_float2(v.x, v.y); q2b = make_float2(v.z, v.w);
            v = rb[3]; q3a = make_float2(v.x, v.y); q3b = make_float2(v.z, v.w);
            v = rb[4]; q4a = make_float2(v.x, v.y); q4b = make_float2(v.z, v.w);
            v = rb[5]; q5a = make_float2(v.x, v.y); q5b = make_float2(v.z, v.w);
        }

        const int qyB = yq * 12 + y0C;
        unsigned int mb0 = 0, mb1 = 0, mb2 = 0;
        if (cact) {
            int o0 = qyB + 0 + sy; if (o0 >= W48) o0 -= W48;
            int o1 = qyB + 1 + sy; if (o1 >= W48) o1 -= W48;
            int o2 = qyB + 2 + sy; if (o2 >= W48) o2 -= W48;
            mb0 = (unsigned)(t * HW + o0 * W48);
            mb1 = (unsigned)(t * HW + o1 * W48);
            mb2 = (unsigned)(t * HW + o2 * W48);
        }
        int rx = xc + sx0; if (rx >= W48) rx -= W48;

        double bst0 = DMAXD, bst1 = DMAXD, bst2 = DMAXD;

        STEP2(0,  6, q0a, q0b, q1a, q1b, q2a, q2b, q3a, q3b);
        STEP2(2,  8, q2a, q2b, q3a, q3b, q4a, q4b, q5a, q5b);
        STEP2(0, 10, q4a, q4b, q5a, q5b, q0a, q0b, q1a, q1b);
        STEP2(2, 12, q0a, q0b, q1a, q1b, q2a, q2b, q3a, q3b);
        STEP2(0, 14, q2a, q2b, q3a, q3b, q4a, q4b, q5a, q5b);
        STEP2(2, 16, q4a, q4b, q5a, q5b, q0a, q0b, q1a, q1b);
        STEP2(0, 18, q0a, q0b, q1a, q1b, q2a, q2b, q3a, q3b);
        STEP2(2, 20, q2a, q2b, q3a, q3b, q4a, q4b, q5a, q5b);
        STEP2(0, 22, q4a, q4b, q5a, q5b, q0a, q0b, q1a, q1b);
        STEP2(2, 24, q0a, q0b, q1a, q1b, q2a, q2b, q3a, q3b);
        STEP2(0, 26, q2a, q2b, q3a, q3b, q4a, q4b, q5a, q5b);
        STEP2(2, 28, q4a, q4b, q5a, q5b, q0a, q0b, q1a, q1b);

        if (cact) {
            unsigned long long* bt =
                best_part + (size_t)t * HW + qyB * W48 + xc;
            atomicMin(&bt[0 * W48], (unsigned long long)
                      __double_as_longlong(bst0));
            atomicMin(&bt[1 * W48], (unsigned long long)
                      __double_as_longlong(bst1));
            atomicMin(&bt[2 * W48], (unsigned long long)
                      __double_as_longlong(bst2));
        }
    }
#undef STEP2
#undef COLMIN
#undef DIFFP
}

// ---------------------------------------------------------------------------
// gather: reduce per-t partials; gather center pixel of (t+1) patch; write
// output frame + next carry + per-element sq-error; re-init best_part.
// ---------------------------------------------------------------------------
__global__ __launch_bounds__(256) void gather_kernel(
    unsigned long long* __restrict__ best_part,
    const float4* __restrict__ rec4, const float* __restrict__ x,
    const float* __restrict__ walls,
    float4* __restrict__ curnext, float* __restrict__ dout,
    float* __restrict__ err, int step)
{
    int p = blockIdx.x * 256 + threadIdx.x;
    if (p >= HW) return;
    unsigned long long bestv = ~0ULL;
#pragma unroll
    for (int j = 0; j < NT; j++) {
        unsigned long long v = best_part[(size_t)j * HW + p];
        bestv = v < bestv ? v : bestv;
    }
#pragma unroll
    for (int j = 0; j < NT; j++) {
        best_part[(size_t)j * HW + p] = ~0ULL;
    }
    unsigned int m = (unsigned int)bestv;
    int t = m / HW, qq = m % HW;
    float4 v = rec4[(t + 1) * HW + qq];
    curnext[p] = v;
    dout[(step + 1) * 3 * HW + 0 * HW + p] = v.x;
    dout[(step + 1) * 3 * HW + 1 * HW + p] = v.y;
    dout[(step + 1) * 3 * HW + 2 * HW + p] = v.z;
    float t0 = x[((step + 1) * 3 + 0) * HW + p];
    float t1 = x[((step + 1) * 3 + 1) * HW + p];
    float t2 = x[((step + 1) * 3 + 2) * HW + p];
    float t3 = walls[p];
    float e = (v.x - t0) * (v.x - t0) + (v.y - t1) * (v.y - t1) +
              (v.z - t2) * (v.z - t2) + (v.w - t3) * (v.w - t3);
    err[step * HW + p] = e;
}

// ---------------------------------------------------------------------------
// loss: deterministic reduction; loss = total / 18432.
// ---------------------------------------------------------------------------
__global__ __launch_bounds__(256) void loss_kernel(
    const float* __restrict__ err, float* __restrict__ dout)
{
    __shared__ float ssum[256];
    float s = 0.f;
    for (int i = threadIdx.x; i < 2 * HW; i += 256) s += err[i];
    ssum[threadIdx.x] = s;
    __syncthreads();
    for (int w = 128; w > 0; w >>= 1) {
        if (threadIdx.x < w) ssum[threadIdx.x] += ssum[threadIdx.x + w];
        __syncthreads();
    }
    if (threadIdx.x == 0) dout[9 * HW] = ssum[0] / 18432.0f;
}

extern "C" void kernel_launch(void* const* d_in, const int* in_sizes, int n_in,
                              void* d_out, int out_size, void* d_ws,
                              size_t ws_size, hipStream_t stream)
{
    const float* x     = (const float*)d_in[0];
    const float* rec   = (const float*)d_in[1];
    const float* walls = (const float*)d_in[2];
    float* dout = (float*)d_out;

    char* ws = (char*)d_ws;
    float4* rec4  = (float4*)ws;                                // 589824 B
    float4* rec4x = (float4*)(ws + 589824);                     // 1572864 B
    float4* curb  = (float4*)(ws + 589824 + 1572864);           // 110592 B
    float*  err   = (float*)(ws + 589824 + 1572864 + 110592);   // 18432 B
    unsigned long long* best_part =
        (unsigned long long*)(ws + 589824 + 1572864 + 110592 + 18432);
    unsigned int* ctr =
        (unsigned int*)(ws + 589824 + 1572864 + 110592 + 18432 + 276480);

    prep_kernel<<<144, 256, 0, stream>>>(x, rec, walls, rec4, rec4x, curb,
                                         dout, best_part, ctr);
    for (int step = 0; step < 2; step++) {
        dist_kernel<<<2048, 256, 0, stream>>>(rec4x, curb + step * HW,
                                              best_part, ctr + step);
        gather_kernel<<<9, 256, 0, stream>>>(best_part, rec4, x, walls,
                                             curb + (step + 1) * HW, dout, err,
                                             step);
    }
    loss_kernel<<<1, 256, 0, stream>>>(err, dout);
}

// Round 17
// 130.186 us; speedup vs baseline: 1.6766x; 1.6766x over previous
//
#include <hip/hip_runtime.h>

#define HW 2304
#define W48 48
#define NT 15              // timestep partials for the atomic spread
#define RST 17             // transposed Rs: [48 cols][17 rows-pad] floats
#define RS_SIZE (W48 * RST)
#define RXW 128            // rec4x row width (float4), col c holds rec[c%48]

// ---------------------------------------------------------------------------
// prep: build rec4 (flat, for gather) + rec4x (row-duplicated width-128, for
// dist's literal-offset ring refills) + cur0 + frame-0 output copy, and
// initialize best_part (replaces the first hipMemsetAsync).
// ---------------------------------------------------------------------------
__global__ __launch_bounds__(256) void prep_kernel(
    const float* __restrict__ x, const float* __restrict__ rec,
    const float* __restrict__ walls,
    float4* __restrict__ rec4, float4* __restrict__ rec4x,
    float4* __restrict__ cur0, float* __restrict__ dout,
    unsigned long long* __restrict__ best_part)
{
    int id = blockIdx.x * 256 + threadIdx.x;
    if (id < 16 * HW) {
        int t = id / HW, p = id % HW;
        int y = p / W48, xx = p % W48;
        float4 v = make_float4(rec[(t * 3 + 0) * HW + p],
                               rec[(t * 3 + 1) * HW + p],
                               rec[(t * 3 + 2) * HW + p],
                               walls[p]);
        rec4[id] = v;
        float4* rowd = rec4x + (size_t)(t * W48 + y) * RXW;
        rowd[xx] = v;
        rowd[xx + 48] = v;
        if (xx < 32) rowd[xx + 96] = v;
    }
    if (id < HW) {
        cur0[id] = make_float4(x[0 * HW + id], x[1 * HW + id], x[2 * HW + id],
                               walls[id]);
    }
    if (id < 3 * HW) {
        dout[id] = x[id];  // frame 0, channels 0..2
    }
    if (id < NT * HW) {
        best_part[id] = ~0ULL;
    }
}

// DPP within 16-lane rows. ROW_ROR:N (0x120+N): dest lane i <- src lane
// (i-N) mod 16. Direction pinned by r8's verified row_shl:N = i<-i+N.
template <int CTL>
__device__ __forceinline__ float dppf(float v)
{
    return __int_as_float(__builtin_amdgcn_update_dpp(
        0, __float_as_int(v), CTL, 0xF, 0xF, false));
}
#define ROR1  0x121   // lane i <- lane (i-1) mod 16  (left neighbor's value)
#define ROR15 0x12F   // lane i <- lane (i+1) mod 16  (right neighbor's value)

// ---------------------------------------------------------------------------
// dist v17: r15 verbatim (block = (t, sy, y-quarter, sx-half), 5760 launched
// blocks x 256 threads, 4 transposed Rs buffers + 1 barrier per fused
// sx-pair, DPP halo, literal-offset 6-slot ring, packed-fp32 DIFF) + ONE
// isolated r16 piece: packed argmin via fmin(double). Packed
// (dist_bits<<32|idx) is a positive finite double (dist < +inf => exp <
// 0x7FF), so IEEE double ordering == u64 ordering; v_min_f64 = 1 inst vs
// cmp_lt_u64 + 2 cndmask. (r16's regression was the work-stealing loop:
// per-item setup serialization + VGPR 36->48; launched blocks overlap setup
// via the dispatcher.) Distances/indices bit-identical to rounds 2..16.
// ---------------------------------------------------------------------------
__global__ __launch_bounds__(256) void dist_kernel(
    const float4* __restrict__ rec4x, const float4* __restrict__ cur4,
    unsigned long long* __restrict__ best_part)
{
    __shared__ float Rs[4 * RS_SIZE];      // 13056 B

    const int tid = threadIdx.x;
    const int b   = blockIdx.x;
    const int t   = b / 384;
    const int rem = b % 384;
    const int sy  = rem >> 3;
    const int q   = rem & 7;
    const int yq  = q >> 1;          // y-quarter: output rows yq*12..yq*12+11
    const int sx0 = (q & 1) * 24;    // sx half: sx0..sx0+23

    // A ownership: F-local row rid (0..15), cols x0..x0+2
    const int rid = tid >> 4;
    const int cA  = tid & 15;
    const int x0  = 3 * cA;
    int qy = yq * 12 + rid - 2;
    if (qy < 0) qy += W48;
    if (qy >= W48) qy -= W48;
    int ry = qy + sy; if (ry >= W48) ry -= W48;

    const float4* curRow = cur4 + qy * W48;
    const float4 c0 = curRow[x0 + 0];
    const float4 c1 = curRow[x0 + 1];
    const float4 c2 = curRow[x0 + 2];
    const float2 cw0a = make_float2(c0.x, c0.y), cw0b = make_float2(c0.z, c0.w);
    const float2 cw1a = make_float2(c1.x, c1.y), cw1b = make_float2(c1.z, c1.w);
    const float2 cw2a = make_float2(c2.x, c2.y), cw2b = make_float2(c2.z, c2.w);

    // duplicated rec row base: rb[j] = rec[t][ry][(cb+j)%48], j < 128-cb
    const int cb = x0 + sx0;
    const float4* rb = rec4x + (size_t)(t * W48 + ry) * RXW + cb;

    // 6-slot named ring held as float2 pairs (subreg halves of float4 loads)
    float2 q0a, q0b, q1a, q1b, q2a, q2b, q3a, q3b, q4a, q4b, q5a, q5b;
    {
        float4 v;
        v = rb[0]; q0a = make_float2(v.x, v.y); q0b = make_float2(v.z, v.w);
        v = rb[1]; q1a = make_float2(v.x, v.y); q1b = make_float2(v.z, v.w);
        v = rb[2]; q2a = make_float2(v.x, v.y); q2b = make_float2(v.z, v.w);
        v = rb[3]; q3a = make_float2(v.x, v.y); q3b = make_float2(v.z, v.w);
        v = rb[4]; q4a = make_float2(v.x, v.y); q4b = make_float2(v.z, v.w);
        v = rb[5]; q5a = make_float2(v.x, v.y); q5b = make_float2(v.z, v.w);
    }

    // C ownership (tid < 192): col xc, output rows qyB..qyB+2
    const bool cact = tid < 192;
    const int xc  = tid % W48;
    const int y0C = 3 * (tid / W48);       // 0,3,6,9 for active threads
    const int qyB = yq * 12 + y0C;
    unsigned int mb0 = 0, mb1 = 0, mb2 = 0;
    if (cact) {
        int o0 = qyB + 0 + sy; if (o0 >= W48) o0 -= W48;
        int o1 = qyB + 1 + sy; if (o1 >= W48) o1 -= W48;
        int o2 = qyB + 2 + sy; if (o2 >= W48) o2 -= W48;
        mb0 = (unsigned)(t * HW + o0 * W48);
        mb1 = (unsigned)(t * HW + o1 * W48);
        mb2 = (unsigned)(t * HW + o2 * W48);
    }
    int rx = xc + sx0; if (rx >= W48) rx -= W48;   // candidate col (xc+sx)%48

    const double DMAXD = __longlong_as_double(0x7FEFFFFFFFFFFFFFLL);
    double bst0 = DMAXD, bst1 = DMAXD, bst2 = DMAXD;

// packed-fp32 squared diff over 4 channels (two float2 halves)
#define DIFFP(F, CAa, CAb, WAa, WAb) do {                                   \
        float2 dA_ = (CAa) - (WAa);                                         \
        float2 dB_ = (CAb) - (WAb);                                         \
        float2 s_  = dA_ * dA_ + dB_ * dB_;                                 \
        F = s_.x + s_.y;                                                    \
    } while (0)

#define COLMIN(BUF, RX) do {                                                \
        const float* rp = &Rs[(BUF) * RS_SIZE + xc * RST + y0C];            \
        float rv0 = rp[0], rv1 = rp[1], rv2 = rp[2], rv3 = rp[3];           \
        float rv4 = rp[4], rv5 = rp[5], rv6 = rp[6];                        \
        float U_ = rv2 + rv3 + rv4;                                         \
        float D0 = rv0 + rv1 + U_;                                          \
        float D1 = rv1 + U_ + rv5;                                          \
        float D2 = U_ + rv5 + rv6;                                          \
        bst0 = fmin(bst0, __longlong_as_double((long long)(                 \
            ((unsigned long long)__float_as_uint(D0) << 32) |               \
            (mb0 + (unsigned)(RX)))));                                      \
        bst1 = fmin(bst1, __longlong_as_double((long long)(                 \
            ((unsigned long long)__float_as_uint(D1) << 32) |               \
            (mb1 + (unsigned)(RX)))));                                      \
        bst2 = fmin(bst2, __longlong_as_double((long long)(                 \
            ((unsigned long long)__float_as_uint(D2) << 32) |               \
            (mb2 + (unsigned)(RX)))));                                      \
    } while (0)

// STEP2: sx pair. Even sx uses ring slots (A0,A1,A2); odd uses (A1,A2,A3).
// Halo via DPP row_ror. Writes bufs PB, PB+1 (transposed); one barrier; C
// reads both; refills A0,A1 from rb[J], rb[J+1] (literal offsets).
#define STEP2(PB, J, A0a, A0b, A1a, A1b, A2a, A2b, A3a, A3b) do {           \
        float F0a, F1a, F2a, F0b, F1b, F2b;                                 \
        DIFFP(F0a, cw0a, cw0b, A0a, A0b);                                   \
        DIFFP(F1a, cw1a, cw1b, A1a, A1b);                                   \
        DIFFP(F2a, cw2a, cw2b, A2a, A2b);                                   \
        DIFFP(F0b, cw0a, cw0b, A1a, A1b);                                   \
        DIFFP(F1b, cw1a, cw1b, A2a, A2b);                                   \
        DIFFP(F2b, cw2a, cw2b, A3a, A3b);                                   \
        float Fm2a = dppf<ROR1>(F1a);                                       \
        float Fm1a = dppf<ROR1>(F2a);                                       \
        float F3a  = dppf<ROR15>(F0a);                                      \
        float F4a  = dppf<ROR15>(F1a);                                      \
        float Fm2b = dppf<ROR1>(F1b);                                       \
        float Fm1b = dppf<ROR1>(F2b);                                       \
        float F3b  = dppf<ROR15>(F0b);                                      \
        float F4b  = dppf<ROR15>(F1b);                                      \
        float Ta  = F0a + F1a + F2a;                                        \
        float R0a = Fm2a + Fm1a + Ta;                                       \
        float R1a = Fm1a + Ta + F3a;                                        \
        float R2a = Ta + F3a + F4a;                                         \
        float Tb  = F0b + F1b + F2b;                                        \
        float R0b = Fm2b + Fm1b + Tb;                                       \
        float R1b = Fm1b + Tb + F3b;                                        \
        float R2b = Tb + F3b + F4b;                                         \
        {                                                                   \
            float* wa = &Rs[(PB) * RS_SIZE + x0 * RST + rid];               \
            wa[0 * RST] = R0a; wa[1 * RST] = R1a; wa[2 * RST] = R2a;        \
            float* wb = &Rs[((PB) + 1) * RS_SIZE + x0 * RST + rid];         \
            wb[0 * RST] = R0b; wb[1 * RST] = R1b; wb[2 * RST] = R2b;        \
        }                                                                   \
        {                                                                   \
            float4 v_;                                                      \
            v_ = rb[J];                                                     \
            A0a = make_float2(v_.x, v_.y); A0b = make_float2(v_.z, v_.w);   \
            v_ = rb[(J) + 1];                                               \
            A1a = make_float2(v_.x, v_.y); A1b = make_float2(v_.z, v_.w);   \
        }                                                                   \
        __syncthreads();                                                    \
        if (cact) {                                                         \
            int rxB = rx + 1; if (rxB >= W48) rxB -= W48;                   \
            COLMIN(PB, rx);                                                 \
            COLMIN((PB) + 1, rxB);                                          \
            rx = rxB + 1; if (rx >= W48) rx -= W48;                         \
        } else {                                                            \
            rx += 2; if (rx >= W48) rx -= W48;                              \
        }                                                                   \
    } while (0)

    STEP2(0,  6, q0a, q0b, q1a, q1b, q2a, q2b, q3a, q3b);
    STEP2(2,  8, q2a, q2b, q3a, q3b, q4a, q4b, q5a, q5b);
    STEP2(0, 10, q4a, q4b, q5a, q5b, q0a, q0b, q1a, q1b);
    STEP2(2, 12, q0a, q0b, q1a, q1b, q2a, q2b, q3a, q3b);
    STEP2(0, 14, q2a, q2b, q3a, q3b, q4a, q4b, q5a, q5b);
    STEP2(2, 16, q4a, q4b, q5a, q5b, q0a, q0b, q1a, q1b);
    STEP2(0, 18, q0a, q0b, q1a, q1b, q2a, q2b, q3a, q3b);
    STEP2(2, 20, q2a, q2b, q3a, q3b, q4a, q4b, q5a, q5b);
    STEP2(0, 22, q4a, q4b, q5a, q5b, q0a, q0b, q1a, q1b);
    STEP2(2, 24, q0a, q0b, q1a, q1b, q2a, q2b, q3a, q3b);
    STEP2(0, 26, q2a, q2b, q3a, q3b, q4a, q4b, q5a, q5b);
    STEP2(2, 28, q4a, q4b, q5a, q5b, q0a, q0b, q1a, q1b);
#undef STEP2
#undef COLMIN
#undef DIFFP

    if (cact) {
        unsigned long long* bt = best_part + (size_t)t * HW + qyB * W48 + xc;
        atomicMin(&bt[0 * W48],
                  (unsigned long long)__double_as_longlong(bst0));
        atomicMin(&bt[1 * W48],
                  (unsigned long long)__double_as_longlong(bst1));
        atomicMin(&bt[2 * W48],
                  (unsigned long long)__double_as_longlong(bst2));
    }
}

// ---------------------------------------------------------------------------
// gather: reduce per-t partials; gather center pixel of (t+1) patch; write
// output frame + next carry + per-element sq-error; re-init best_part for
// the next dist launch (same-thread, race-free).
// ---------------------------------------------------------------------------
__global__ __launch_bounds__(256) void gather_kernel(
    unsigned long long* __restrict__ best_part,
    const float4* __restrict__ rec4, const float* __restrict__ x,
    const float* __restrict__ walls,
    float4* __restrict__ curnext, float* __restrict__ dout,
    float* __restrict__ err, int step)
{
    int p = blockIdx.x * 256 + threadIdx.x;
    if (p >= HW) return;
    unsigned long long bestv = ~0ULL;
#pragma unroll
    for (int j = 0; j < NT; j++) {
        unsigned long long v = best_part[(size_t)j * HW + p];
        bestv = v < bestv ? v : bestv;
    }
#pragma unroll
    for (int j = 0; j < NT; j++) {
        best_part[(size_t)j * HW + p] = ~0ULL;
    }
    unsigned int m = (unsigned int)bestv;
    int t = m / HW, qq = m % HW;
    float4 v = rec4[(t + 1) * HW + qq];
    curnext[p] = v;
    dout[(step + 1) * 3 * HW + 0 * HW + p] = v.x;
    dout[(step + 1) * 3 * HW + 1 * HW + p] = v.y;
    dout[(step + 1) * 3 * HW + 2 * HW + p] = v.z;
    float t0 = x[((step + 1) * 3 + 0) * HW + p];
    float t1 = x[((step + 1) * 3 + 1) * HW + p];
    float t2 = x[((step + 1) * 3 + 2) * HW + p];
    float t3 = walls[p];
    float e = (v.x - t0) * (v.x - t0) + (v.y - t1) * (v.y - t1) +
              (v.z - t2) * (v.z - t2) + (v.w - t3) * (v.w - t3);
    err[step * HW + p] = e;
}

// ---------------------------------------------------------------------------
// loss: deterministic reduction; loss = total / 18432.
// ---------------------------------------------------------------------------
__global__ __launch_bounds__(256) void loss_kernel(
    const float* __restrict__ err, float* __restrict__ dout)
{
    __shared__ float ssum[256];
    float s = 0.f;
    for (int i = threadIdx.x; i < 2 * HW; i += 256) s += err[i];
    ssum[threadIdx.x] = s;
    __syncthreads();
    for (int w = 128; w > 0; w >>= 1) {
        if (threadIdx.x < w) ssum[threadIdx.x] += ssum[threadIdx.x + w];
        __syncthreads();
    }
    if (threadIdx.x == 0) dout[9 * HW] = ssum[0] / 18432.0f;
}

extern "C" void kernel_launch(void* const* d_in, const int* in_sizes, int n_in,
                              void* d_out, int out_size, void* d_ws,
                              size_t ws_size, hipStream_t stream)
{
    const float* x     = (const float*)d_in[0];
    const float* rec   = (const float*)d_in[1];
    const float* walls = (const float*)d_in[2];
    float* dout = (float*)d_out;

    char* ws = (char*)d_ws;
    float4* rec4  = (float4*)ws;                                // 589824 B
    float4* rec4x = (float4*)(ws + 589824);                     // 1572864 B
    float4* curb  = (float4*)(ws + 589824 + 1572864);           // 110592 B
    float*  err   = (float*)(ws + 589824 + 1572864 + 110592);   // 18432 B
    unsigned long long* best_part =
        (unsigned long long*)(ws + 589824 + 1572864 + 110592 + 18432);

    prep_kernel<<<144, 256, 0, stream>>>(x, rec, walls, rec4, rec4x, curb,
                                         dout, best_part);
    for (int step = 0; step < 2; step++) {
        dist_kernel<<<NT * W48 * 8, 256, 0, stream>>>(rec4x, curb + step * HW,
                                                      best_part);
        gather_kernel<<<9, 256, 0, stream>>>(best_part, rec4, x, walls,
                                             curb + (step + 1) * HW, dout, err,
                                             step);
    }
    loss_kernel<<<1, 256, 0, stream>>>(err, dout);
}